// Round 12
// baseline (709.328 us; speedup 1.0000x reference)
//
#include <hip/hip_runtime.h>
#include <stdint.h>

#define B_ 8
#define L_ 2500
#define D_ 512
#define Y_ 8921
#define LP 2560   // padded L = 20*128
#define YP 8960   // padded Y = 70*128
#define BLK 128   // y-tile and l-tile
#define BK 32
#define NKT 16    // 512/32
#define NS 4      // l-splits
#define LTS 5     // l-tiles of 128 per split (20/NS)
#define NSLOT (LTS * NKT)     // 80 pipeline slots per block
#define RING 4                // LDS ring slots
#define SLOTU16 12288         // u16 per slot: U 4096 | W 4096 | X 4096 (24 KB)
#define NBLK (70 * B_ * NS)   // 2240 blocks
#define PERX (NBLK / 8)       // 280 work items per XCD

typedef float f32x4 __attribute__((ext_vector_type(4)));
typedef __bf16 bf16x8 __attribute__((ext_vector_type(8)));
typedef unsigned short u16;
typedef unsigned int u32;

// ---- f32 -> bf16 (RTNE) pack helpers ----
__device__ __forceinline__ u32 pack2(float a, float b) {
  u32 ua = __float_as_uint(a); ua = (ua + 0x7FFFu + ((ua >> 16) & 1u)) >> 16;
  u32 ub = __float_as_uint(b); ub = (ub + 0x7FFFu + ((ub >> 16) & 1u)) >> 16;
  return ua | (ub << 16);
}

// x [B,L,D] f32 -> [B,LP,D] bf16 (pad rows zero)
__global__ void cvt_x_kernel(const float* __restrict__ x, u16* __restrict__ xb) {
  int idx = blockIdx.x * 256 + threadIdx.x;   // one 8-elem chunk
  int row = idx >> 6;                         // b*LP + l
  int c8  = (idx & 63) << 3;
  int b = row / LP;
  int l = row - b * LP;
  uint4 o;
  if (l < L_) {
    const float* s = x + (size_t)(b * L_ + l) * D_ + c8;
    float4 f0 = *(const float4*)s;
    float4 f1 = *(const float4*)(s + 4);
    o.x = pack2(f0.x, f0.y); o.y = pack2(f0.z, f0.w);
    o.z = pack2(f1.x, f1.y); o.w = pack2(f1.z, f1.w);
  } else {
    o = make_uint4(0u, 0u, 0u, 0u);
  }
  *(uint4*)(xb + (size_t)row * D_ + c8) = o;
}

// U,Wf [Y,D] f32 -> [YP,D] bf16 each (pad rows zero)
__global__ void cvt_w_kernel(const float* __restrict__ U, const float* __restrict__ Wf,
                             u16* __restrict__ Ub, u16* __restrict__ Wb) {
  int idx = blockIdx.x * 256 + threadIdx.x;
  const int half = YP * 64;
  const float* src = U; u16* dst = Ub;
  int i = idx;
  if (idx >= half) { i -= half; src = Wf; dst = Wb; }
  int row = i >> 6;
  int c8  = (i & 63) << 3;
  uint4 o;
  if (row < Y_) {
    const float* s = src + (size_t)row * D_ + c8;
    float4 f0 = *(const float4*)s;
    float4 f1 = *(const float4*)(s + 4);
    o.x = pack2(f0.x, f0.y); o.y = pack2(f0.z, f0.w);
    o.z = pack2(f1.x, f1.y); o.w = pack2(f1.z, f1.w);
  } else {
    o = make_uint4(0u, 0u, 0u, 0u);
  }
  *(uint4*)(dst + (size_t)row * D_ + c8) = o;
}

__device__ __forceinline__ void async16(const u16* g, u16* l) {
  __builtin_amdgcn_global_load_lds(
      (const __attribute__((address_space(1))) u32*)g,
      (__attribute__((address_space(3))) u32*)l, 16, 0, 0);
}

// ===== Producer-consumer fused kernel =====
// R0-R11: skeleton (no VMEM) ~ MFMA floor; VMEM in the compute stream = +327us,
// invariant under vmcnt/prefetch/barrier/byte manipulation. THIS round moves
// ALL VMEM to a dedicated producer wave (wave 4): 4 compute waves run a pure
// {ds_read -> MFMA -> softmax} stream with NO barriers, NO VMEM. LDS ring of
// 4 x 24KB slots; flag semaphores (ready/done monotonic counters) in LDS.
// Producer: counted vmcnt(24) publishes (never drains mid-loop). 96KB LDS ->
// exactly 1 block/CU; 5 waves -> one per SIMD (+producer sharing SIMD0).
//
// Partial layout: part[((b*70 + yt)*NS + s)*384 + {0,128,256} + ylocal]
__global__ __launch_bounds__(320, 1) void fused_kernel(
    const u16* __restrict__ xb,   // [B][LP][D] bf16
    const u16* __restrict__ Ub,   // [YP][D]
    const u16* __restrict__ Wb,   // [YP][D]
    float* __restrict__ part)
{
  __shared__ __align__(16) u16 sRing[RING * SLOTU16];   // 96 KB
  __shared__ unsigned ready[RING];   // per-buffer publication count
  __shared__ unsigned done[RING];    // per-buffer consumption count (4/round)

  const int t    = threadIdx.x;
  const int lane = t & 63;
  const int wv   = t >> 6;          // 0..3 compute, 4 producer

  // XCD-contiguous work id: bid%8 = XCD; yt slow within an XCD (U/W L2-hot)
  const int bid = blockIdx.x;
  const int w   = (bid & 7) * PERX + (bid >> 3);
  const int yt  = w >> 5;           // 0..69
  const int rem = w & 31;
  const int b   = rem >> 2;         // 0..7
  const int s   = rem & 3;          // l-split 0..3
  const int y0  = yt * BLK;

  if (t < RING)            ready[t] = 0u;
  else if (t < 2 * RING)   done[t - RING] = 0u;
  __syncthreads();                  // the only block-wide barrier

  if (wv == 4) {
    // ================= PRODUCER =================
    const int p = lane;
    const u16* bU = Ub + (size_t)(y0 + (p >> 2)) * D_ + (p & 3) * 8;
    const u16* bW = Wb + (size_t)(y0 + (p >> 2)) * D_ + (p & 3) * 8;
    const u16* bX = xb + ((size_t)b * LP + s * (LTS * BLK) + (p >> 2)) * D_ + (p & 3) * 8;
    u16* lbase = sRing + p * 8;

#pragma unroll 1
    for (int n = 0; n < NSLOT; ++n) {
      const int buf = n & (RING - 1);
      const unsigned round = (unsigned)(n >> 2);
      if (round > 0) {   // wait until buffer's previous round fully consumed
        while (((volatile unsigned*)done)[buf] < 4u * round)
          __builtin_amdgcn_s_sleep(1);
      }
      asm volatile("" ::: "memory");
      const int kt  = n & (NKT - 1);
      const int ltl = n >> 4;
      u16* dst = lbase + buf * SLOTU16;
      const u16* pu = bU + kt * BK;
      const u16* pw = bW + kt * BK;
      const u16* px = bX + (size_t)(ltl * BLK) * D_ + kt * BK;
#pragma unroll
      for (int j8 = 0; j8 < 8; ++j8) {
        async16(pu + (size_t)(j8 * 16) * D_, dst + j8 * 512);
        async16(pw + (size_t)(j8 * 16) * D_, dst + 4096 + j8 * 512);
        async16(px + (size_t)(j8 * 16) * D_, dst + 8192 + j8 * 512);
      }
      if (n >= 1) {
        // slot n-1's 24 loads retired (<=24 outstanding = slot n's own)
        asm volatile("s_waitcnt vmcnt(24)" ::: "memory");
        const int pb = (n - 1) & (RING - 1);
        ((volatile unsigned*)ready)[pb] = (unsigned)(((n - 1) >> 2) + 1);
        asm volatile("" ::: "memory");
      }
    }
    asm volatile("s_waitcnt vmcnt(0)" ::: "memory");
    ((volatile unsigned*)ready)[(NSLOT - 1) & (RING - 1)] =
        (unsigned)(((NSLOT - 1) >> 2) + 1);
    return;
  }

  // ================= CONSUMERS (4 waves, one per SIMD) =================
  const int l16 = lane & 15;
  const int q   = lane >> 4;        // quad 0..3
  const int offU = (wv * 32 + l16) * BK + q * 8;   // u16, within slot

  float M[8], Z[8], W[8];
#pragma unroll
  for (int i = 0; i < 8; ++i) { M[i] = -1e30f; Z[i] = 0.f; W[i] = 0.f; }

  const f32x4 z4 = {0.f, 0.f, 0.f, 0.f};
  int n = 0;

  for (int ltl = 0; ltl < LTS; ++ltl) {
    f32x4 accA[2][8], accS[2][8];
#pragma unroll
    for (int ry = 0; ry < 2; ++ry)
#pragma unroll
      for (int cl = 0; cl < 8; ++cl) { accA[ry][cl] = z4; accS[ry][cl] = z4; }

#pragma unroll 1
    for (int kt = 0; kt < NKT; ++kt, ++n) {
      const int buf = n & (RING - 1);
      const unsigned want = (unsigned)((n >> 2) + 1);
      while (((volatile unsigned*)ready)[buf] < want)
        __builtin_amdgcn_s_sleep(1);
      asm volatile("" ::: "memory");
      __builtin_amdgcn_sched_barrier(0);   // no ds_read hoisted above the poll

      const u16* bb = sRing + buf * SLOTU16;
      bf16x8 aU0 = *(const bf16x8*)(const void*)(bb + offU);
      bf16x8 aU1 = *(const bf16x8*)(const void*)(bb + offU + 16 * BK);
      bf16x8 aW0 = *(const bf16x8*)(const void*)(bb + 4096 + offU);
      bf16x8 aW1 = *(const bf16x8*)(const void*)(bb + 4096 + offU + 16 * BK);
      bf16x8 xf[8];
#pragma unroll
      for (int cl = 0; cl < 8; ++cl)
        xf[cl] = *(const bf16x8*)(const void*)(bb + 8192 + (cl * 16 + l16) * BK + q * 8);

      __builtin_amdgcn_s_setprio(1);
#pragma unroll
      for (int cl = 0; cl < 8; ++cl) {
        accA[0][cl] = __builtin_amdgcn_mfma_f32_16x16x32_bf16(aU0, xf[cl], accA[0][cl], 0, 0, 0);
        accA[1][cl] = __builtin_amdgcn_mfma_f32_16x16x32_bf16(aU1, xf[cl], accA[1][cl], 0, 0, 0);
        accS[0][cl] = __builtin_amdgcn_mfma_f32_16x16x32_bf16(aW0, xf[cl], accS[0][cl], 0, 0, 0);
        accS[1][cl] = __builtin_amdgcn_mfma_f32_16x16x32_bf16(aW1, xf[cl], accS[1][cl], 0, 0, 0);
      }
      __builtin_amdgcn_s_setprio(0);

      // reads fully retired (operands in regs) -> release the buffer
      asm volatile("s_waitcnt lgkmcnt(0)" ::: "memory");
      __builtin_amdgcn_sched_barrier(0);
      if (lane == 0) atomicAdd(&done[buf], 1u);
    }

    // per-lane online softmax update. C/D: col(l)=lane&15, row(y)=q*4+reg
    const int l0 = (s * LTS + ltl) * BLK;
    const bool boundary = (l0 + BLK > L_);   // wave-uniform; 1 of 20 tiles
#pragma unroll
    for (int ry = 0; ry < 2; ++ry) {
#pragma unroll
      for (int r = 0; r < 4; ++r) {
        const int si = ry * 4 + r;
        float a[8];
        if (boundary) {
#pragma unroll
          for (int cl = 0; cl < 8; ++cl) {
            float v = accA[ry][cl][r];
            a[cl] = (l0 + cl * 16 + l16 >= L_) ? -1e30f : v;
          }
        } else {
#pragma unroll
          for (int cl = 0; cl < 8; ++cl) a[cl] = accA[ry][cl][r];
        }
        float tmax = a[0];
#pragma unroll
        for (int cl = 1; cl < 8; ++cl) tmax = fmaxf(tmax, a[cl]);
        const float mnew  = fmaxf(M[si], tmax);
        const float scale = __expf(M[si] - mnew);
        float zl = 0.f, wl = 0.f;
#pragma unroll
        for (int cl = 0; cl < 8; ++cl) {
          float p = __expf(a[cl] - mnew);
          zl += p;
          wl = fmaf(p, accS[ry][cl][r], wl);
        }
        Z[si] = fmaf(Z[si], scale, zl);
        W[si] = fmaf(W[si], scale, wl);
        M[si] = mnew;
      }
    }
  }

  // ONE cross-lane merge over the l16 group (butterfly with exp rescale)
#pragma unroll
  for (int si = 0; si < 8; ++si) {
    float M0 = M[si], Z0 = Z[si], W0 = W[si];
#pragma unroll
    for (int st = 1; st <= 8; st <<= 1) {
      const float Mo = __shfl_xor(M0, st);
      const float Zo = __shfl_xor(Z0, st);
      const float Wo = __shfl_xor(W0, st);
      const float mn = fmaxf(M0, Mo);
      const float sa = __expf(M0 - mn);
      const float sb = __expf(Mo - mn);
      Z0 = Z0 * sa + Zo * sb;
      W0 = W0 * sa + Wo * sb;
      M0 = mn;
    }
    M[si] = M0; Z[si] = Z0; W[si] = W0;
  }

  // write partial (M,Z,W) per owned y-row; stats replicated -> l16==0 writes
  if (l16 == 0) {
    float* p = part + ((size_t)(b * 70 + yt) * NS + s) * 384;
#pragma unroll
    for (int ry = 0; ry < 2; ++ry) {
#pragma unroll
      for (int r = 0; r < 4; ++r) {
        const int si = ry * 4 + r;
        const int yl = wv * 32 + ry * 16 + q * 4 + r;
        p[yl]       = M[si];
        p[128 + yl] = Z[si];
        p[256 + yl] = W[si];
      }
    }
  }
}

// Merge NS partials per (b,y); y = W/Z + bias; BCE partial -> atomicAdd.
__global__ void combine_kernel(const float* __restrict__ part,
                               const float* __restrict__ bias,
                               const float* __restrict__ target,
                               float* __restrict__ out) {
  const int idx = blockIdx.x * 256 + threadIdx.x;
  float lpart = 0.f;
  if (idx < B_ * Y_) {
    const int b = idx / Y_;
    const int y = idx - b * Y_;
    const int yt = y >> 7, yl = y & 127;
    const float* p = part + ((size_t)(b * 70 + yt) * NS) * 384 + yl;
    float M = -1e30f;
#pragma unroll
    for (int s2 = 0; s2 < NS; ++s2) M = fmaxf(M, p[s2 * 384]);
    float Z = 0.f, W = 0.f;
#pragma unroll
    for (int s2 = 0; s2 < NS; ++s2) {
      const float e = __expf(p[s2 * 384] - M);
      Z = fmaf(p[s2 * 384 + 128], e, Z);
      W = fmaf(p[s2 * 384 + 256], e, W);
    }
    const float yv = W / Z + bias[y];
    out[idx] = yv;
    const float tg = target[idx];
    lpart = fmaxf(yv, 0.f) - yv * tg + log1pf(__expf(-fabsf(yv)));
  }
  lpart += __shfl_xor(lpart, 1);  lpart += __shfl_xor(lpart, 2);
  lpart += __shfl_xor(lpart, 4);  lpart += __shfl_xor(lpart, 8);
  lpart += __shfl_xor(lpart, 16); lpart += __shfl_xor(lpart, 32);
  if ((threadIdx.x & 63) == 0)
    atomicAdd(out + (size_t)B_ * Y_, lpart * (1.0f / (B_ * Y_)));
}

extern "C" void kernel_launch(void* const* d_in, const int* in_sizes, int n_in,
                              void* d_out, int out_size, void* d_ws, size_t ws_size,
                              hipStream_t stream) {
  const float* x      = (const float*)d_in[0];
  const float* target = (const float*)d_in[1];
  // d_in[2] = text_inputs (unused by reference)
  const float* U      = (const float*)d_in[3];
  const float* Wf     = (const float*)d_in[4];
  const float* bias   = (const float*)d_in[5];
  float* out = (float*)d_out;

  u16* xb = (u16*)d_ws;                      // [B][LP][D]   20.97 MB
  u16* Ub = xb + (size_t)B_ * LP * D_;       // [YP][D]       9.18 MB
  u16* Wb = Ub + (size_t)YP * D_;            // [YP][D]       9.18 MB
  float* part = (float*)(Wb + (size_t)YP * D_);  // [B][70][NS][384] f32  3.44 MB

  hipMemsetAsync(out + (size_t)B_ * Y_, 0, sizeof(float), stream);
  cvt_x_kernel<<<dim3((B_ * LP * 64) / 256), 256, 0, stream>>>(x, xb);
  cvt_w_kernel<<<dim3((2 * YP * 64) / 256), 256, 0, stream>>>(U, Wf, Ub, Wb);
  fused_kernel<<<dim3(NBLK), 320, 0, stream>>>(xb, Ub, Wb, part);
  combine_kernel<<<dim3((B_ * Y_ + 255) / 256), 256, 0, stream>>>(part, bias, target, out);
}

// Round 13
// 643.796 us; speedup vs baseline: 1.1018x; 1.1018x over previous
//
#include <hip/hip_runtime.h>
#include <stdint.h>

#define B_ 8
#define L_ 2500
#define D_ 512
#define Y_ 8921
#define LP 2560    // padded L = 10*256
#define YP 8960    // padded Y = 70*128
#define BY 128     // y-tile per block
#define BL 256     // l-tile per block
#define BK 32
#define NKT 16     // 512/32 K-steps
#define NSP 10     // l-splits
#define NBLK (70 * B_ * NSP)   // 5600 blocks
#define PERX (NBLK / 8)        // 700 work items per XCD
#define SLOT 16384 // u16 per ring slot (32 KB): U 4K | W 4K | X 8K
#define RING 4     // ring slots (128 KB LDS)

typedef float f32x4 __attribute__((ext_vector_type(4)));
typedef __bf16 bf16x8 __attribute__((ext_vector_type(8)));
typedef unsigned short u16;
typedef unsigned int u32;

// ---- f32 -> bf16 (RTNE) pack helpers ----
__device__ __forceinline__ u32 pack2(float a, float b) {
  u32 ua = __float_as_uint(a); ua = (ua + 0x7FFFu + ((ua >> 16) & 1u)) >> 16;
  u32 ub = __float_as_uint(b); ub = (ub + 0x7FFFu + ((ub >> 16) & 1u)) >> 16;
  return ua | (ub << 16);
}

__global__ void cvt_x_kernel(const float* __restrict__ x, u16* __restrict__ xb) {
  int idx = blockIdx.x * 256 + threadIdx.x;
  int row = idx >> 6;
  int c8  = (idx & 63) << 3;
  int b = row / LP;
  int l = row - b * LP;
  uint4 o;
  if (l < L_) {
    const float* s = x + (size_t)(b * L_ + l) * D_ + c8;
    float4 f0 = *(const float4*)s;
    float4 f1 = *(const float4*)(s + 4);
    o.x = pack2(f0.x, f0.y); o.y = pack2(f0.z, f0.w);
    o.z = pack2(f1.x, f1.y); o.w = pack2(f1.z, f1.w);
  } else {
    o = make_uint4(0u, 0u, 0u, 0u);
  }
  *(uint4*)(xb + (size_t)row * D_ + c8) = o;
}

__global__ void cvt_w_kernel(const float* __restrict__ U, const float* __restrict__ Wf,
                             u16* __restrict__ Ub, u16* __restrict__ Wb) {
  int idx = blockIdx.x * 256 + threadIdx.x;
  const int half = YP * 64;
  const float* src = U; u16* dst = Ub;
  int i = idx;
  if (idx >= half) { i -= half; src = Wf; dst = Wb; }
  int row = i >> 6;
  int c8  = (i & 63) << 3;
  uint4 o;
  if (row < Y_) {
    const float* s = src + (size_t)row * D_ + c8;
    float4 f0 = *(const float4*)s;
    float4 f1 = *(const float4*)(s + 4);
    o.x = pack2(f0.x, f0.y); o.y = pack2(f0.z, f0.w);
    o.z = pack2(f1.x, f1.y); o.w = pack2(f1.z, f1.w);
  } else {
    o = make_uint4(0u, 0u, 0u, 0u);
  }
  *(uint4*)(dst + (size_t)row * D_ + c8) = o;
}

__device__ __forceinline__ void async16(const u16* g, u16* l) {
  __builtin_amdgcn_global_load_lds(
      (const __attribute__((address_space(1))) u32*)g,
      (__attribute__((address_space(3))) u32*)l, 16, 0, 0);
}

// ===== m201-template port: 4-slot ring, 2 fine phases/K-step, counted vmcnt,
// T2 chunk-XOR swizzle, T5 setprio. Per block: y=128 x l=256, K=512 (16 x 32).
// 8 waves (2y x 4l); each wave: 64x64 patch of BOTH U- and W-products.
// Ring slot: U[128][32] | W[128][32] | X[256][32], chunk c at row r holds
// global chunk c^(r&3) (staged via pre-swizzled SOURCE, linear LDS dest;
// read side applies the same XOR -- both-sides-or-neither).
// Prefetch 2 K-steps ahead; per-step wait = vmcnt(4) (never 0 mid-loop).
//
// Partial layout: part[((b*70 + yt)*NSP + s)*384 + {0,128,256} + ylocal]
__global__ __launch_bounds__(512, 1) void fused_kernel(
    const u16* __restrict__ xb,   // [B][LP][D] bf16
    const u16* __restrict__ Ub,   // [YP][D]
    const u16* __restrict__ Wb,   // [YP][D]
    float* __restrict__ part)
{
  __shared__ __align__(16) u16 sRing[RING * SLOT];   // 128 KB
  __shared__ float sSt[3 * 4 * BY];                  // 6 KB cross-wl merge

  const int t    = threadIdx.x;
  const int lane = t & 63;
  const int wv   = t >> 6;          // 0..7
  const int wy   = wv >> 2;         // 0..1 : y-half  [wy*64, +64)
  const int wl   = wv & 3;          // 0..3 : l-quarter [wl*64, +64)
  const int l16  = lane & 15;
  const int q    = lane >> 4;       // quad 0..3
  const int swz  = ((q ^ (l16 & 3)) << 3);   // read-side chunk XOR (u16 units)

  // XCD-contiguous work id: bid%8 = XCD; yt slow within an XCD (U/W L2-hot)
  const int bid = blockIdx.x;
  const int w   = (bid & 7) * PERX + (bid >> 3);
  const int yt  = w / 80;           // 0..69
  const int rem = w - yt * 80;
  const int b   = rem / NSP;        // 0..7
  const int s   = rem - b * NSP;    // 0..9
  const int y0  = yt * BY;
  const int l0  = s * BL;

  // staging: thread t covers row t>>2, LDS chunk t&3; global source chunk is
  // pre-swizzled: (t&3) ^ (row&3)  [involution; read XOR matches]
  const int srow = t >> 2;                       // 0..127
  const int scol = (((t & 3) ^ (srow & 3)) << 3);
  const u16* gU  = Ub + (size_t)(y0 + srow) * D_ + scol;
  const u16* gW  = Wb + (size_t)(y0 + srow) * D_ + scol;
  const u16* gX0 = xb + ((size_t)b * LP + l0 + srow) * D_ + scol;
  const u16* gX1 = gX0 + (size_t)128 * D_;

  const f32x4 z4 = {0.f, 0.f, 0.f, 0.f};
  f32x4 accA[4][4], accS[4][4];
#pragma unroll
  for (int yi = 0; yi < 4; ++yi)
#pragma unroll
    for (int xi = 0; xi < 4; ++xi) { accA[yi][xi] = z4; accS[yi][xi] = z4; }

  // prologue: fully stage steps 0 and 1; wait step 0 (leave step 1 in flight)
  {
    u16* s0 = sRing;            u16* s1 = sRing + SLOT;
    async16(gU,       s0 + t * 8);          async16(gX0,      s0 + 8192 + t * 8);
    async16(gW,       s0 + 4096 + t * 8);   async16(gX1,      s0 + 12288 + t * 8);
    async16(gU + BK,  s1 + t * 8);          async16(gX0 + BK, s1 + 8192 + t * 8);
    async16(gW + BK,  s1 + 4096 + t * 8);   async16(gX1 + BK, s1 + 12288 + t * 8);
    asm volatile("s_waitcnt vmcnt(4)" ::: "memory");
    __builtin_amdgcn_s_barrier();
    asm volatile("" ::: "memory");
  }

#pragma unroll 1
  for (int ts = 0; ts < NKT; ++ts) {
    const u16* sl = sRing + (ts & 3) * SLOT;
    const int t2 = ts + 2;
    u16* sp = sRing + (t2 & 3) * SLOT;   // prefetch dest (slot of step ts+2)
    const int ko2 = t2 * BK;

    // ---------- PHASE 1: U x X ----------
    bf16x8 uf[4], xf[4];
#pragma unroll
    for (int i = 0; i < 4; ++i) {
      uf[i] = *(const bf16x8*)(const void*)(sl + (wy * 64 + i * 16 + l16) * 32 + swz);
      xf[i] = *(const bf16x8*)(const void*)(sl + 8192 + (wl * 64 + i * 16 + l16) * 32 + swz);
    }
    if (t2 < NKT) {
      async16(gU + ko2,  sp + t * 8);
      async16(gX0 + ko2, sp + 8192 + t * 8);
    }
    asm volatile("" ::: "memory");
    __builtin_amdgcn_s_barrier();
    asm volatile("" ::: "memory");
    __builtin_amdgcn_s_setprio(1);
#pragma unroll
    for (int yi = 0; yi < 4; ++yi)
#pragma unroll
      for (int xi = 0; xi < 4; ++xi)
        accA[yi][xi] = __builtin_amdgcn_mfma_f32_16x16x32_bf16(uf[yi], xf[xi], accA[yi][xi], 0, 0, 0);
    __builtin_amdgcn_s_setprio(0);
    asm volatile("" ::: "memory");
    __builtin_amdgcn_s_barrier();
    asm volatile("" ::: "memory");

    // ---------- PHASE 2: W x X ----------
    bf16x8 wf[4];
#pragma unroll
    for (int i = 0; i < 4; ++i)
      wf[i] = *(const bf16x8*)(const void*)(sl + 4096 + (wy * 64 + i * 16 + l16) * 32 + swz);
    if (t2 < NKT) {
      async16(gW + ko2,  sp + 4096 + t * 8);
      async16(gX1 + ko2, sp + 12288 + t * 8);
    }
    if (ts + 1 < NKT) {
      if (t2 < NKT) asm volatile("s_waitcnt vmcnt(4)" ::: "memory");  // step ts+1 ready; ts+2 in flight
      else          asm volatile("s_waitcnt vmcnt(0)" ::: "memory");  // pipeline tail
    }
    asm volatile("" ::: "memory");
    __builtin_amdgcn_s_barrier();
    asm volatile("" ::: "memory");
    __builtin_amdgcn_s_setprio(1);
#pragma unroll
    for (int yi = 0; yi < 4; ++yi)
#pragma unroll
      for (int xi = 0; xi < 4; ++xi)
        accS[yi][xi] = __builtin_amdgcn_mfma_f32_16x16x32_bf16(wf[yi], xf[xi], accS[yi][xi], 0, 0, 0);
    __builtin_amdgcn_s_setprio(0);
    asm volatile("" ::: "memory");
    __builtin_amdgcn_s_barrier();
    asm volatile("" ::: "memory");
  }

  // ---- one-shot per-lane softmax stats over this block's 256 l-cols ----
  // C/D: col(l)=lane&15 within 16-block, row(y)=q*4+reg.
  float M[16], Z[16], W[16];
  const bool boundary = (l0 + BL > L_);             // s==9 only
#pragma unroll
  for (int yi = 0; yi < 4; ++yi) {
#pragma unroll
    for (int r = 0; r < 4; ++r) {
      const int si = yi * 4 + r;
      float a[4];
#pragma unroll
      for (int xi = 0; xi < 4; ++xi) {
        float v = accA[yi][xi][r];
        a[xi] = (boundary && (l0 + wl * 64 + xi * 16 + l16 >= L_)) ? -1e30f : v;
      }
      const float mx = fmaxf(fmaxf(a[0], a[1]), fmaxf(a[2], a[3]));
      float zl = 0.f, wl_ = 0.f;
#pragma unroll
      for (int xi = 0; xi < 4; ++xi) {
        const float p = __expf(a[xi] - mx);
        zl += p;
        wl_ = fmaf(p, accS[yi][xi][r], wl_);
      }
      M[si] = mx; Z[si] = zl; W[si] = wl_;
    }
  }

  // cross-lane merge over the l16 group (butterfly with exp rescale)
#pragma unroll
  for (int si = 0; si < 16; ++si) {
    float M0 = M[si], Z0 = Z[si], W0 = W[si];
#pragma unroll
    for (int st = 1; st <= 8; st <<= 1) {
      const float Mo = __shfl_xor(M0, st);
      const float Zo = __shfl_xor(Z0, st);
      const float Wo = __shfl_xor(W0, st);
      const float mn = fmaxf(M0, Mo);
      const float sa = __expf(M0 - mn);
      const float sb = __expf(Mo - mn);
      Z0 = Z0 * sa + Zo * sb;
      W0 = W0 * sa + Wo * sb;
      M0 = mn;
    }
    M[si] = M0; Z[si] = Z0; W[si] = W0;
  }

  // cross-wl merge via LDS: each wl wave publishes its 128-y stats
  __syncthreads();
  if (l16 == 0) {
#pragma unroll
    for (int yi = 0; yi < 4; ++yi) {
#pragma unroll
      for (int r = 0; r < 4; ++r) {
        const int si = yi * 4 + r;
        const int yloc = wy * 64 + yi * 16 + q * 4 + r;
        sSt[wl * BY + yloc]        = M[si];
        sSt[512 + wl * BY + yloc]  = Z[si];
        sSt[1024 + wl * BY + yloc] = W[si];
      }
    }
  }
  __syncthreads();
  if (t < BY) {
    float Mm = sSt[t];
#pragma unroll
    for (int k = 1; k < 4; ++k) Mm = fmaxf(Mm, sSt[k * BY + t]);
    float Zm = 0.f, Wm = 0.f;
#pragma unroll
    for (int k = 0; k < 4; ++k) {
      const float e = __expf(sSt[k * BY + t] - Mm);
      Zm = fmaf(sSt[512 + k * BY + t], e, Zm);
      Wm = fmaf(sSt[1024 + k * BY + t], e, Wm);
    }
    float* p = part + ((size_t)(b * 70 + yt) * NSP + s) * 384;
    p[t]       = Mm;
    p[128 + t] = Zm;
    p[256 + t] = Wm;
  }
}

// Merge NSP partials per (b,y); y = W/Z + bias; BCE partial -> atomicAdd.
__global__ void combine_kernel(const float* __restrict__ part,
                               const float* __restrict__ bias,
                               const float* __restrict__ target,
                               float* __restrict__ out) {
  const int idx = blockIdx.x * 256 + threadIdx.x;
  float lpart = 0.f;
  if (idx < B_ * Y_) {
    const int b = idx / Y_;
    const int y = idx - b * Y_;
    const int yt = y >> 7, yl = y & 127;
    const float* p = part + ((size_t)(b * 70 + yt) * NSP) * 384 + yl;
    float M = -1e30f;
#pragma unroll
    for (int s2 = 0; s2 < NSP; ++s2) M = fmaxf(M, p[s2 * 384]);
    float Z = 0.f, W = 0.f;
#pragma unroll
    for (int s2 = 0; s2 < NSP; ++s2) {
      const float e = __expf(p[s2 * 384] - M);
      Z = fmaf(p[s2 * 384 + 128], e, Z);
      W = fmaf(p[s2 * 384 + 256], e, W);
    }
    const float yv = W / Z + bias[y];
    out[idx] = yv;
    const float tg = target[idx];
    lpart = fmaxf(yv, 0.f) - yv * tg + log1pf(__expf(-fabsf(yv)));
  }
  lpart += __shfl_xor(lpart, 1);  lpart += __shfl_xor(lpart, 2);
  lpart += __shfl_xor(lpart, 4);  lpart += __shfl_xor(lpart, 8);
  lpart += __shfl_xor(lpart, 16); lpart += __shfl_xor(lpart, 32);
  if ((threadIdx.x & 63) == 0)
    atomicAdd(out + (size_t)B_ * Y_, lpart * (1.0f / (B_ * Y_)));
}

extern "C" void kernel_launch(void* const* d_in, const int* in_sizes, int n_in,
                              void* d_out, int out_size, void* d_ws, size_t ws_size,
                              hipStream_t stream) {
  const float* x      = (const float*)d_in[0];
  const float* target = (const float*)d_in[1];
  // d_in[2] = text_inputs (unused by reference)
  const float* U      = (const float*)d_in[3];
  const float* Wf     = (const float*)d_in[4];
  const float* bias   = (const float*)d_in[5];
  float* out = (float*)d_out;

  u16* xb = (u16*)d_ws;                      // [B][LP][D]   20.97 MB
  u16* Ub = xb + (size_t)B_ * LP * D_;       // [YP][D]       9.18 MB
  u16* Wb = Ub + (size_t)YP * D_;            // [YP][D]       9.18 MB
  float* part = (float*)(Wb + (size_t)YP * D_);  // [B][70][NSP][384] f32  8.6 MB

  hipMemsetAsync(out + (size_t)B_ * Y_, 0, sizeof(float), stream);
  cvt_x_kernel<<<dim3((B_ * LP * 64) / 256), 256, 0, stream>>>(x, xb);
  cvt_w_kernel<<<dim3((2 * YP * 64) / 256), 256, 0, stream>>>(U, Wf, Ub, Wb);
  fused_kernel<<<dim3(NBLK), 512, 0, stream>>>(xb, Ub, Wb, part);
  combine_kernel<<<dim3((B_ * Y_ + 255) / 256), 256, 0, stream>>>(part, bias, target, out);
}

// Round 14
// 573.552 us; speedup vs baseline: 1.2367x; 1.1225x over previous
//
#include <hip/hip_runtime.h>
#include <stdint.h>

#define B_ 8
#define L_ 2500
#define D_ 512
#define Y_ 8921
#define LP 2560   // padded L = 20*128
#define YP 8960   // padded Y = 70*128
#define BLK 128   // y-tile and l-tile
#define BK 32
#define NPAIR 4   // barrier-pairs per l-tile (each stages 4 k-slices = 128 k)
#define NS 4      // l-splits
#define LTS 5     // l-tiles of 128 per split (20/NS)
#define NBLK (70 * B_ * NS)   // 2240 blocks
#define PERX (NBLK / 8)       // 280 work items per XCD

typedef float f32x4 __attribute__((ext_vector_type(4)));
typedef __bf16 bf16x8 __attribute__((ext_vector_type(8)));
typedef unsigned short u16;
typedef unsigned int u32;

// ---- f32 -> bf16 (RTNE) pack helpers ----
__device__ __forceinline__ u32 pack2(float a, float b) {
  u32 ua = __float_as_uint(a); ua = (ua + 0x7FFFu + ((ua >> 16) & 1u)) >> 16;
  u32 ub = __float_as_uint(b); ub = (ub + 0x7FFFu + ((ub >> 16) & 1u)) >> 16;
  return ua | (ub << 16);
}

// Merged conversion: x [B,L,D] f32 -> [B,LP,D] bf16 AND U,Wf [Y,D] f32 ->
// [YP,D] bf16 each, in ONE launch (the two original kernels serialized on the
// stream; merging saves a launch gap and packs the BW better).
// Block range [0, NXB): x chunks. [NXB, NXB+NWB): U/W chunks.
#define NXCHUNK (B_ * LP * 64)
#define NWCHUNK (2 * YP * 64)
__global__ void cvt_all_kernel(const float* __restrict__ x,
                               const float* __restrict__ U,
                               const float* __restrict__ Wf,
                               u16* __restrict__ xb,
                               u16* __restrict__ Ub,
                               u16* __restrict__ Wb) {
  int idx = blockIdx.x * 256 + threadIdx.x;
  if (idx < NXCHUNK) {
    // ---- x path ----
    int row = idx >> 6;                         // b*LP + l
    int c8  = (idx & 63) << 3;
    int b = row / LP;
    int l = row - b * LP;
    uint4 o;
    if (l < L_) {
      const float* s = x + (size_t)(b * L_ + l) * D_ + c8;
      float4 f0 = *(const float4*)s;
      float4 f1 = *(const float4*)(s + 4);
      o.x = pack2(f0.x, f0.y); o.y = pack2(f0.z, f0.w);
      o.z = pack2(f1.x, f1.y); o.w = pack2(f1.z, f1.w);
    } else {
      o = make_uint4(0u, 0u, 0u, 0u);
    }
    *(uint4*)(xb + (size_t)row * D_ + c8) = o;
  } else {
    // ---- U/W path ----
    int i = idx - NXCHUNK;
    const int half = YP * 64;
    const float* src = U; u16* dst = Ub;
    if (i >= half) { i -= half; src = Wf; dst = Wb; }
    int row = i >> 6;
    int c8  = (i & 63) << 3;
    uint4 o;
    if (row < Y_) {
      const float* s = src + (size_t)row * D_ + c8;
      float4 f0 = *(const float4*)s;
      float4 f1 = *(const float4*)(s + 4);
      o.x = pack2(f0.x, f0.y); o.y = pack2(f0.z, f0.w);
      o.z = pack2(f1.x, f1.y); o.w = pack2(f1.z, f1.w);
    } else {
      o = make_uint4(0u, 0u, 0u, 0u);
    }
    *(uint4*)(dst + (size_t)row * D_ + c8) = o;
  }
}

__device__ __forceinline__ void async16(const u16* g, u16* l) {
  __builtin_amdgcn_global_load_lds(
      (const __attribute__((address_space(1))) u32*)g,
      (__attribute__((address_space(3))) u32*)l, 16, 0, 0);
}

// Fused per (y-tile 128, b, l-split): stream LTS l-tiles of 128, MFMA att & s,
// per-lane online softmax (cross-lane merge once at kernel end).
//
// BEST-MEASURED STRUCTURE (R7, 503us fused / 573.95 total) -- kept verbatim.
// 14-round session conclusion: per-wave-step latency is pinned ~3400cy
// regardless of content (drain/ds/A-load waits absorb each other), and
// concurrency is register-capped at 2 waves/SIMD (acc = 128 f32 = half the
// 256-reg/wave file, fixed by the output-tile/reuse tradeoff). Wall ~=
// wave-steps x 3400 / waves-per-SIMD ~= 500us -- reproduced by 4 independent
// structures; every graft (counted vmcnt, occupancy, fewer bytes, fewer
// barriers, A-prefetch, no-lockstep, producer-consumer, m201 template) is
// null-to-negative.
//
// Partial layout: part[((b*70 + yt)*NS + s)*384 + {0,128,256} + ylocal]
__global__ __launch_bounds__(256, 2) void fused_kernel(
    const u16* __restrict__ xb,   // [B][LP][D] bf16
    const u16* __restrict__ Ub,   // [YP][D]
    const u16* __restrict__ Wb,   // [YP][D]
    float* __restrict__ part)
{
  __shared__ __align__(16) u16 sX[4 * BLK * BK];   // four [128][32] slices, 32 KB

  const int t    = threadIdx.x;
  const int lane = t & 63;
  const int wv   = t >> 6;          // wave 0..3, owns y rows [wv*32, wv*32+32)
  const int l16  = lane & 15;
  const int q    = lane >> 4;       // quad 0..3

  // XCD-contiguous work id: bid%8 = XCD (round-robin dispatch)
  const int bid = blockIdx.x;
  const int w   = (bid & 7) * PERX + (bid >> 3);
  const int yt  = w >> 5;           // 0..69  (slow within an XCD)
  const int rem = w & 31;
  const int b   = rem >> 2;         // 0..7
  const int s   = rem & 3;          // l-split 0..3
  const int y0  = yt * BLK;

  // X staging: thread t loads 16B chunk: row = t>>2 (+64 for 2nd op), chunk (t&3)*8
  const int srow = t >> 2;
  const int scol = (t & 3) << 3;
  const u16* gXb = xb + (size_t)b * LP * D_ + (size_t)srow * D_ + scol;

  // A-fragment global pointers (per-lane): rows y0+wv*32+l16 (+16), k chunk q*8.
  // Wave covers 16 rows x 64 B = 16 full cache lines per load op. L2-hot.
  const u16* fU0 = Ub + (size_t)(y0 + wv * 32 + l16) * D_ + q * 8;
  const u16* fU1 = fU0 + (size_t)16 * D_;
  const u16* fW0 = Wb + (size_t)(y0 + wv * 32 + l16) * D_ + q * 8;
  const u16* fW1 = fW0 + (size_t)16 * D_;

  // PER-LANE running softmax stats: lane covers cols (cl*16+l16), cl=0..7,
  // for each of its 8 y-rows (si = ry*4+r).
  float M[8], Z[8], W[8];
#pragma unroll
  for (int i = 0; i < 8; ++i) { M[i] = -1e30f; Z[i] = 0.f; W[i] = 0.f; }

  const f32x4 z4 = {0.f, 0.f, 0.f, 0.f};

  for (int ltl = 0; ltl < LTS; ++ltl) {
    const int l0 = (s * LTS + ltl) * BLK;
    const u16* gX0 = gXb + (size_t)l0 * D_;
    const u16* gX1 = gX0 + (size_t)64 * D_;

    f32x4 accA[2][8], accS[2][8];
#pragma unroll
    for (int ry = 0; ry < 2; ++ry)
#pragma unroll
      for (int cl = 0; cl < 8; ++cl) { accA[ry][cl] = z4; accS[ry][cl] = z4; }

#pragma unroll 1
    for (int pair = 0; pair < NPAIR; ++pair) {
      const int pko = pair * 128;
      __syncthreads();                 // previous pair's slices consumed
      async16(gX0 + pko,      sX + t * 8);
      async16(gX1 + pko,      sX + 2048 + t * 8);
      async16(gX0 + pko + 32, sX + 4096 + t * 8);
      async16(gX1 + pko + 32, sX + 4096 + 2048 + t * 8);
      async16(gX0 + pko + 64, sX + 8192 + t * 8);
      async16(gX1 + pko + 64, sX + 8192 + 2048 + t * 8);
      async16(gX0 + pko + 96, sX + 12288 + t * 8);
      async16(gX1 + pko + 96, sX + 12288 + 2048 + t * 8);
      __syncthreads();                 // all 4 slices visible (vmcnt drain)

#pragma unroll 1
      for (int kk = 0; kk < 4; ++kk) {
        const int ko = pko + kk * BK;
        bf16x8 aU0 = *(const bf16x8*)(const void*)(fU0 + ko);
        bf16x8 aU1 = *(const bf16x8*)(const void*)(fU1 + ko);
        bf16x8 aW0 = *(const bf16x8*)(const void*)(fW0 + ko);
        bf16x8 aW1 = *(const bf16x8*)(const void*)(fW1 + ko);
        const u16* bXb = sX + kk * 4096;
#pragma unroll
        for (int cl = 0; cl < 8; ++cl) {
          bf16x8 bX = *(const bf16x8*)(const void*)(bXb + (cl * 16 + l16) * BK + q * 8);
          accA[0][cl] = __builtin_amdgcn_mfma_f32_16x16x32_bf16(aU0, bX, accA[0][cl], 0, 0, 0);
          accA[1][cl] = __builtin_amdgcn_mfma_f32_16x16x32_bf16(aU1, bX, accA[1][cl], 0, 0, 0);
          accS[0][cl] = __builtin_amdgcn_mfma_f32_16x16x32_bf16(aW0, bX, accS[0][cl], 0, 0, 0);
          accS[1][cl] = __builtin_amdgcn_mfma_f32_16x16x32_bf16(aW1, bX, accS[1][cl], 0, 0, 0);
        }
      }
    }

    // per-lane online softmax update. C/D: col(l)=lane&15, row(y)=q*4+reg
    const bool boundary = (l0 + BLK > L_);   // wave-uniform; 1 of 20 tiles
#pragma unroll
    for (int ry = 0; ry < 2; ++ry) {
#pragma unroll
      for (int r = 0; r < 4; ++r) {
        const int si = ry * 4 + r;
        float a[8];
        if (boundary) {
#pragma unroll
          for (int cl = 0; cl < 8; ++cl) {
            float v = accA[ry][cl][r];
            a[cl] = (l0 + cl * 16 + l16 >= L_) ? -1e30f : v;
          }
        } else {
#pragma unroll
          for (int cl = 0; cl < 8; ++cl) a[cl] = accA[ry][cl][r];
        }
        float tmax = a[0];
#pragma unroll
        for (int cl = 1; cl < 8; ++cl) tmax = fmaxf(tmax, a[cl]);
        const float mnew  = fmaxf(M[si], tmax);
        const float scale = __expf(M[si] - mnew);
        float zl = 0.f, wl = 0.f;
#pragma unroll
        for (int cl = 0; cl < 8; ++cl) {
          float p = __expf(a[cl] - mnew);
          zl += p;
          wl = fmaf(p, accS[ry][cl][r], wl);
        }
        Z[si] = fmaf(Z[si], scale, zl);
        W[si] = fmaf(W[si], scale, wl);
        M[si] = mnew;
      }
    }
  }

  // ONE cross-lane merge over the l16 group (butterfly with exp rescale)
#pragma unroll
  for (int si = 0; si < 8; ++si) {
    float M0 = M[si], Z0 = Z[si], W0 = W[si];
#pragma unroll
    for (int st = 1; st <= 8; st <<= 1) {
      const float Mo = __shfl_xor(M0, st);
      const float Zo = __shfl_xor(Z0, st);
      const float Wo = __shfl_xor(W0, st);
      const float mn = fmaxf(M0, Mo);
      const float sa = __expf(M0 - mn);
      const float sb = __expf(Mo - mn);
      Z0 = Z0 * sa + Zo * sb;
      W0 = W0 * sa + Wo * sb;
      M0 = mn;
    }
    M[si] = M0; Z[si] = Z0; W[si] = W0;
  }

  // write partial (M,Z,W) per owned y-row; stats now replicated -> l16==0 writes
  if (l16 == 0) {
    float* p = part + ((size_t)(b * 70 + yt) * NS + s) * 384;
#pragma unroll
    for (int ry = 0; ry < 2; ++ry) {
#pragma unroll
      for (int r = 0; r < 4; ++r) {
        const int si = ry * 4 + r;
        const int yl = wv * 32 + ry * 16 + q * 4 + r;
        p[yl]       = M[si];
        p[128 + yl] = Z[si];
        p[256 + yl] = W[si];
      }
    }
  }
}

// Merge NS partials per (b,y); y = W/Z + bias; BCE partial -> atomicAdd.
__global__ void combine_kernel(const float* __restrict__ part,
                               const float* __restrict__ bias,
                               const float* __restrict__ target,
                               float* __restrict__ out) {
  const int idx = blockIdx.x * 256 + threadIdx.x;
  float lpart = 0.f;
  if (idx < B_ * Y_) {
    const int b = idx / Y_;
    const int y = idx - b * Y_;
    const int yt = y >> 7, yl = y & 127;
    const float* p = part + ((size_t)(b * 70 + yt) * NS) * 384 + yl;
    float M = -1e30f;
#pragma unroll
    for (int s2 = 0; s2 < NS; ++s2) M = fmaxf(M, p[s2 * 384]);
    float Z = 0.f, W = 0.f;
#pragma unroll
    for (int s2 = 0; s2 < NS; ++s2) {
      const float e = __expf(p[s2 * 384] - M);
      Z = fmaf(p[s2 * 384 + 128], e, Z);
      W = fmaf(p[s2 * 384 + 256], e, W);
    }
    const float yv = W / Z + bias[y];
    out[idx] = yv;
    const float tg = target[idx];
    lpart = fmaxf(yv, 0.f) - yv * tg + log1pf(__expf(-fabsf(yv)));
  }
  lpart += __shfl_xor(lpart, 1);  lpart += __shfl_xor(lpart, 2);
  lpart += __shfl_xor(lpart, 4);  lpart += __shfl_xor(lpart, 8);
  lpart += __shfl_xor(lpart, 16); lpart += __shfl_xor(lpart, 32);
  if ((threadIdx.x & 63) == 0)
    atomicAdd(out + (size_t)B_ * Y_, lpart * (1.0f / (B_ * Y_)));
}

extern "C" void kernel_launch(void* const* d_in, const int* in_sizes, int n_in,
                              void* d_out, int out_size, void* d_ws, size_t ws_size,
                              hipStream_t stream) {
  const float* x      = (const float*)d_in[0];
  const float* target = (const float*)d_in[1];
  // d_in[2] = text_inputs (unused by reference)
  const float* U      = (const float*)d_in[3];
  const float* Wf     = (const float*)d_in[4];
  const float* bias   = (const float*)d_in[5];
  float* out = (float*)d_out;

  u16* xb = (u16*)d_ws;                      // [B][LP][D]   20.97 MB
  u16* Ub = xb + (size_t)B_ * LP * D_;       // [YP][D]       9.18 MB
  u16* Wb = Ub + (size_t)YP * D_;            // [YP][D]       9.18 MB
  float* part = (float*)(Wb + (size_t)YP * D_);  // [B][70][NS][384] f32  3.44 MB

  hipMemsetAsync(out + (size_t)B_ * Y_, 0, sizeof(float), stream);
  cvt_all_kernel<<<dim3((NXCHUNK + NWCHUNK) / 256), 256, 0, stream>>>(
      x, U, Wf, xb, Ub, Wb);
  fused_kernel<<<dim3(NBLK), 256, 0, stream>>>(xb, Ub, Wb, part);
  combine_kernel<<<dim3((B_ * Y_ + 255) / 256), 256, 0, stream>>>(part, bias, target, out);
}